// Round 1
// baseline (1274.575 us; speedup 1.0000x reference)
//
#include <hip/hip_runtime.h>
#include <math.h>

#define N_NODES 50000
#define N_EDGES 800000
#define C 64
#define H 4
#define D 16
#define HC 256           // H*C
#define NEG_SLOPE 0.2f
#define BN_EPS 1e-5f

// ---------------- projection: out[n, HC] = x[n, :C] @ W[C, HC] ----------------
__global__ void __launch_bounds__(256) proj_kernel(const float* __restrict__ x,
                                                   const float* __restrict__ W,
                                                   float* __restrict__ out) {
    __shared__ float xs[8][C];
    int tid = threadIdx.x;
    int row0 = blockIdx.x * 8;
    for (int i = tid; i < 8 * C; i += 256) {
        int r = i >> 6, k = i & 63;
        xs[r][k] = x[(size_t)(row0 + r) * C + k];
    }
    __syncthreads();
    float acc[8] = {0.f, 0.f, 0.f, 0.f, 0.f, 0.f, 0.f, 0.f};
    for (int k = 0; k < C; ++k) {
        float wk = W[(size_t)k * HC + tid];
#pragma unroll
        for (int r = 0; r < 8; ++r) acc[r] += xs[r][k] * wk;
    }
#pragma unroll
    for (int r = 0; r < 8; ++r)
        out[(size_t)(row0 + r) * HC + tid] = acc[r];
}

// ---------------- per-dst counts + edge_attr sums (for mean self-loop fill) ----------------
__global__ void __launch_bounds__(256) edge_count_kernel(const int* __restrict__ dst,
                                                         const float* __restrict__ ea,
                                                         int* __restrict__ cnt,
                                                         float* __restrict__ loop_sum) {
    int idx = blockIdx.x * 256 + threadIdx.x;
    if (idx >= N_EDGES * D) return;
    int e = idx >> 4, k = idx & 15;
    int d = dst[e];
    atomicAdd(&loop_sum[(size_t)d * D + k], ea[idx]);
    if (k == 0) atomicAdd(&cnt[d], 1);
}

__global__ void __launch_bounds__(256) loop_div_kernel(float* __restrict__ loop_attr,
                                                       const int* __restrict__ cnt) {
    int idx = blockIdx.x * 256 + threadIdx.x;
    if (idx >= N_NODES * D) return;
    int i = idx >> 4;
    loop_attr[idx] /= fmaxf((float)cnt[i], 1.f);
}

// ---------------- exclusive prefix sum over cnt -> csr_off ----------------
__global__ void scan_kernel(const int* __restrict__ cnt, int* __restrict__ off) {
    __shared__ int buf[1024];
    __shared__ int carry_s;
    int tid = threadIdx.x;
    if (tid == 0) { carry_s = 0; off[0] = 0; }
    __syncthreads();
    for (int base = 0; base < N_NODES; base += 1024) {
        int i = base + tid;
        int v = (i < N_NODES) ? cnt[i] : 0;
        buf[tid] = v;
        __syncthreads();
        for (int s = 1; s < 1024; s <<= 1) {
            int t = (tid >= s) ? buf[tid - s] : 0;
            __syncthreads();
            buf[tid] += t;
            __syncthreads();
        }
        int carry = carry_s;
        if (i < N_NODES) off[i + 1] = carry + buf[tid];
        __syncthreads();
        if (tid == 1023) carry_s = carry + buf[1023];
        __syncthreads();
    }
}

__global__ void __launch_bounds__(256) csr_fill_kernel(const int* __restrict__ dst,
                                                       const int* __restrict__ csr_off,
                                                       int* __restrict__ fill,
                                                       int* __restrict__ csr_eid) {
    int e = blockIdx.x * 256 + threadIdx.x;
    if (e >= N_EDGES) return;
    int d = dst[e];
    int pos = csr_off[d] + atomicAdd(&fill[d], 1);
    csr_eid[pos] = e;
}

// ---------------- attention logits: one 64-lane wave per edge ----------------
__global__ void __launch_bounds__(256) logits_kernel(const int* __restrict__ src,
                                                     const int* __restrict__ dst,
                                                     const float* __restrict__ ea,
                                                     const float* __restrict__ loop_attr,
                                                     const float* __restrict__ xl,
                                                     const float* __restrict__ xr,
                                                     const float* __restrict__ We,
                                                     const float* __restrict__ att,
                                                     float* __restrict__ logits) {
    __shared__ float Ws[D * HC];   // 16 KB
    __shared__ float atts[HC];     // 1 KB
    int tid = threadIdx.x;
    for (int i = tid; i < D * HC; i += 256) Ws[i] = We[i];
    for (int i = tid; i < HC; i += 256) atts[i] = att[i];
    __syncthreads();

    int lane = tid & 63;
    int wave = tid >> 6;
    int e = blockIdx.x * 4 + wave;
    if (e >= N_EDGES + N_NODES) return;

    int s, t;
    const float* eap;
    if (e < N_EDGES) { s = src[e]; t = dst[e]; eap = ea + (size_t)e * D; }
    else             { s = t = e - N_EDGES;    eap = loop_attr + (size_t)s * D; }

    float eav[D];
#pragma unroll
    for (int k = 0; k < D; ++k) eav[k] = eap[k];

    const float* xls = xl + (size_t)s * HC;
    const float* xrt = xr + (size_t)t * HC;

#pragma unroll
    for (int h = 0; h < H; ++h) {
        int col = h * C + lane;
        float eev = 0.f;
#pragma unroll
        for (int k = 0; k < D; ++k) eev += eav[k] * Ws[k * HC + col];
        float m = xls[col] + xrt[col] + eev;
        m = (m > 0.f) ? m : NEG_SLOPE * m;
        float v = m * atts[col];
#pragma unroll
        for (int off = 32; off > 0; off >>= 1) v += __shfl_xor(v, off, 64);
        if (lane == 0) logits[(size_t)e * H + h] = v;
    }
}

// ---------------- per-node softmax + weighted aggregation + head mean ----------------
__global__ void __launch_bounds__(256) agg_kernel(const int* __restrict__ srcArr,
                                                  const int* __restrict__ csr_off,
                                                  const int* __restrict__ csr_eid,
                                                  const float* __restrict__ logits,
                                                  const float* __restrict__ xl,
                                                  const float* __restrict__ bias,
                                                  float* __restrict__ out) {
    int i = blockIdx.x;
    int tid = threadIdx.x;
    int h = tid >> 6;
    int off = csr_off[i], end = csr_off[i + 1];
    int deg = end - off;

    __shared__ float4 redm[256];
    __shared__ float redf[256];
    __shared__ float smx[H], sinv[H];

    float4 sl = *(const float4*)(logits + (size_t)(N_EDGES + i) * H);

    // ---- max per head ----
    float m0 = sl.x, m1 = sl.y, m2 = sl.z, m3 = sl.w;
    for (int k = tid; k < deg; k += 256) {
        int e = csr_eid[off + k];
        float4 lg = *(const float4*)(logits + (size_t)e * H);
        m0 = fmaxf(m0, lg.x); m1 = fmaxf(m1, lg.y);
        m2 = fmaxf(m2, lg.z); m3 = fmaxf(m3, lg.w);
    }
    redm[tid] = make_float4(m0, m1, m2, m3);
    __syncthreads();
    for (int s = 128; s > 0; s >>= 1) {
        if (tid < s) {
            float4 a = redm[tid], b = redm[tid + s];
            redm[tid] = make_float4(fmaxf(a.x, b.x), fmaxf(a.y, b.y),
                                    fmaxf(a.z, b.z), fmaxf(a.w, b.w));
        }
        __syncthreads();
    }
    float4 mx4 = redm[0];
    __syncthreads();

    // ---- denominator per head ----
    float d0 = 0.f, d1 = 0.f, d2 = 0.f, d3 = 0.f;
    if (tid == 0) {
        d0 = expf(sl.x - mx4.x); d1 = expf(sl.y - mx4.y);
        d2 = expf(sl.z - mx4.z); d3 = expf(sl.w - mx4.w);
    }
    for (int k = tid; k < deg; k += 256) {
        int e = csr_eid[off + k];
        float4 lg = *(const float4*)(logits + (size_t)e * H);
        d0 += expf(lg.x - mx4.x); d1 += expf(lg.y - mx4.y);
        d2 += expf(lg.z - mx4.z); d3 += expf(lg.w - mx4.w);
    }
    redm[tid] = make_float4(d0, d1, d2, d3);
    __syncthreads();
    for (int s = 128; s > 0; s >>= 1) {
        if (tid < s) {
            float4 a = redm[tid], b = redm[tid + s];
            redm[tid] = make_float4(a.x + b.x, a.y + b.y, a.z + b.z, a.w + b.w);
        }
        __syncthreads();
    }
    if (tid == 0) {
        float4 dn = redm[0];
        smx[0] = mx4.x; smx[1] = mx4.y; smx[2] = mx4.z; smx[3] = mx4.w;
        sinv[0] = 1.f / dn.x; sinv[1] = 1.f / dn.y;
        sinv[2] = 1.f / dn.z; sinv[3] = 1.f / dn.w;
    }
    __syncthreads();

    // ---- weighted aggregation; thread owns (h, c) = (tid>>6, tid&63) ----
    float mxh = smx[h];
    float invh = sinv[h];
    float slh = (h == 0) ? sl.x : (h == 1) ? sl.y : (h == 2) ? sl.z : sl.w;
    float acc = expf(slh - mxh) * invh * xl[(size_t)i * HC + tid];
    for (int k = 0; k < deg; ++k) {
        int e = csr_eid[off + k];
        int s = srcArr[e];
        float lg = logits[(size_t)e * H + h];
        acc += expf(lg - mxh) * invh * xl[(size_t)s * HC + tid];
    }

    // ---- head mean + bias ----
    redf[tid] = acc;
    __syncthreads();
    if (tid < C) {
        float o = (redf[tid] + redf[tid + 64] + redf[tid + 128] + redf[tid + 192]) * 0.25f
                  + bias[tid];
        out[(size_t)i * C + tid] = o;
    }
}

// ---------------- BN statistics (sum, sumsq per channel) ----------------
__global__ void __launch_bounds__(256) bn_stats_kernel(const float* __restrict__ out,
                                                       float* __restrict__ bn) {
    int tid = threadIdx.x;
    int c = tid & 63;
    int r0 = blockIdx.x * 256 + (tid >> 6);
    int rend = (blockIdx.x * 256 + 256 < N_NODES) ? blockIdx.x * 256 + 256 : N_NODES;
    float s = 0.f, s2 = 0.f;
    for (int r = r0; r < rend; r += 4) {
        float v = out[(size_t)r * C + c];
        s += v; s2 += v * v;
    }
    __shared__ float red[256], red2[256];
    red[tid] = s; red2[tid] = s2;
    __syncthreads();
    if (tid < 128) { red[tid] += red[tid + 128]; red2[tid] += red2[tid + 128]; }
    __syncthreads();
    if (tid < 64) {
        atomicAdd(&bn[c], red[tid] + red[tid + 64]);
        atomicAdd(&bn[64 + c], red2[tid] + red2[tid + 64]);
    }
}

// ---------------- BN normalize + residual + ReLU (in place on out) ----------------
__global__ void __launch_bounds__(256) final_kernel(const float* __restrict__ x,
                                                    const float* __restrict__ bn,
                                                    const float* __restrict__ gamma,
                                                    const float* __restrict__ beta,
                                                    float* __restrict__ out) {
    int idx = blockIdx.x * 256 + threadIdx.x;
    if (idx >= N_NODES * C) return;
    int c = idx & 63;
    float mu = bn[c] * (1.f / N_NODES);
    float var = bn[64 + c] * (1.f / N_NODES) - mu * mu;
    float o = out[idx];
    float y = gamma[c] * (o - mu) * rsqrtf(var + BN_EPS) + beta[c] + x[idx];
    out[idx] = fmaxf(y, 0.f);
}

extern "C" void kernel_launch(void* const* d_in, const int* in_sizes, int n_in,
                              void* d_out, int out_size, void* d_ws, size_t ws_size,
                              hipStream_t stream) {
    const float* x     = (const float*)d_in[0];
    const int*   ei    = (const int*)d_in[1];
    const float* ea    = (const float*)d_in[2];
    const float* W_l   = (const float*)d_in[3];
    const float* W_r   = (const float*)d_in[4];
    const float* W_e   = (const float*)d_in[5];
    const float* att   = (const float*)d_in[6];
    const float* bias  = (const float*)d_in[7];
    const float* gamma = (const float*)d_in[8];
    const float* beta  = (const float*)d_in[9];
    float* out = (float*)d_out;

    const int* src = ei;
    const int* dst = ei + N_EDGES;

    char* p = (char*)d_ws;
    float* xl        = (float*)p; p += (size_t)N_NODES * HC * 4;
    float* xr        = (float*)p; p += (size_t)N_NODES * HC * 4;
    float* logits    = (float*)p; p += (size_t)(N_EDGES + N_NODES) * H * 4;
    float* loop_attr = (float*)p; p += (size_t)N_NODES * D * 4;
    float* bn        = (float*)p; p += 512;
    int*   cnt       = (int*)p;   p += (size_t)N_NODES * 4;
    int*   fill      = (int*)p;   p += (size_t)N_NODES * 4;
    int*   csr_off   = (int*)p;   p += (size_t)(N_NODES + 4) * 4;
    int*   csr_eid   = (int*)p;   p += (size_t)N_EDGES * 4;

    // zero loop_attr + bn + cnt + fill (contiguous region)
    hipMemsetAsync(loop_attr, 0,
                   (size_t)N_NODES * D * 4 + 512 + 2 * (size_t)N_NODES * 4, stream);

    proj_kernel<<<N_NODES / 8, 256, 0, stream>>>(x, W_l, xl);
    proj_kernel<<<N_NODES / 8, 256, 0, stream>>>(x, W_r, xr);
    edge_count_kernel<<<(N_EDGES * D) / 256, 256, 0, stream>>>(dst, ea, cnt, loop_attr);
    loop_div_kernel<<<(N_NODES * D) / 256, 256, 0, stream>>>(loop_attr, cnt);
    scan_kernel<<<1, 1024, 0, stream>>>(cnt, csr_off);
    csr_fill_kernel<<<(N_EDGES + 255) / 256, 256, 0, stream>>>(dst, csr_off, fill, csr_eid);
    logits_kernel<<<(N_EDGES + N_NODES + 3) / 4, 256, 0, stream>>>(
        src, dst, ea, loop_attr, xl, xr, W_e, att, logits);
    agg_kernel<<<N_NODES, 256, 0, stream>>>(src, csr_off, csr_eid, logits, xl, bias, out);
    bn_stats_kernel<<<(N_NODES + 255) / 256, 256, 0, stream>>>(out, bn);
    final_kernel<<<(N_NODES * C) / 256, 256, 0, stream>>>(x, bn, gamma, beta, out);
}

// Round 2
// 624.891 us; speedup vs baseline: 2.0397x; 2.0397x over previous
//
#include <hip/hip_runtime.h>
#include <math.h>

#define N_NODES 50000
#define N_EDGES 800000
#define C 64
#define H 4
#define D 16
#define HC 256           // H*C
#define NEG_SLOPE 0.2f
#define BN_EPS 1e-5f
#define MAXD 128         // edges cached in LDS per node (fallback to global past this)

// ---------------- fused projection: xl = x@W_l, xr = x@W_r ----------------
__global__ void __launch_bounds__(256) proj2_kernel(const float* __restrict__ x,
                                                    const float* __restrict__ Wl,
                                                    const float* __restrict__ Wr,
                                                    float* __restrict__ xl,
                                                    float* __restrict__ xr) {
    __shared__ float xs[8][C];
    int tid = threadIdx.x;
    int row0 = blockIdx.x * 8;
    for (int i = tid; i < 8 * C; i += 256) {
        int r = i >> 6, k = i & 63;
        xs[r][k] = x[(size_t)(row0 + r) * C + k];
    }
    __syncthreads();
    float al[8] = {0.f}, ar[8] = {0.f};
    for (int k = 0; k < C; ++k) {
        float wl = Wl[(size_t)k * HC + tid];
        float wr = Wr[(size_t)k * HC + tid];
#pragma unroll
        for (int r = 0; r < 8; ++r) { al[r] += xs[r][k] * wl; ar[r] += xs[r][k] * wr; }
    }
#pragma unroll
    for (int r = 0; r < 8; ++r) {
        xl[(size_t)(row0 + r) * HC + tid] = al[r];
        xr[(size_t)(row0 + r) * HC + tid] = ar[r];
    }
}

// ---------------- per-dst edge counts ----------------
__global__ void __launch_bounds__(256) cnt_kernel(const int* __restrict__ dst,
                                                  int* __restrict__ cnt) {
    int e = blockIdx.x * 256 + threadIdx.x;
    if (e < N_EDGES) atomicAdd(&cnt[dst[e]], 1);
}

// ---------------- exclusive prefix sum over cnt -> csr_off (shfl-based) ----------------
__global__ void scan_kernel(const int* __restrict__ cnt, int* __restrict__ off) {
    __shared__ int wsum[16];
    __shared__ int carry_s;
    int tid = threadIdx.x;
    int lane = tid & 63;
    int w = tid >> 6;
    if (tid == 0) { carry_s = 0; off[0] = 0; }
    __syncthreads();
    for (int base = 0; base < N_NODES; base += 1024) {
        int i = base + tid;
        int v = (i < N_NODES) ? cnt[i] : 0;
        int xv = v;
        for (int o = 1; o < 64; o <<= 1) {
            int t = __shfl_up(xv, o, 64);
            if (lane >= o) xv += t;
        }
        if (lane == 63) wsum[w] = xv;
        __syncthreads();
        if (w == 0 && lane < 16) {
            int y = wsum[lane];
            for (int o = 1; o < 16; o <<= 1) {
                int t = __shfl_up(y, o, 64);
                if (lane >= o) y += t;
            }
            wsum[lane] = y;
        }
        __syncthreads();
        int prefix = carry_s + ((w > 0) ? wsum[w - 1] : 0);
        if (i < N_NODES) off[i + 1] = prefix + xv;
        __syncthreads();
        if (tid == 1023) carry_s = prefix + xv;
        __syncthreads();
    }
}

// ---------------- CSR fill (edge id + src id per slot) ----------------
__global__ void __launch_bounds__(256) csr_fill_kernel(const int* __restrict__ src,
                                                       const int* __restrict__ dst,
                                                       const int* __restrict__ csr_off,
                                                       int* __restrict__ fill,
                                                       int* __restrict__ csr_eid,
                                                       int* __restrict__ csr_src) {
    int e = blockIdx.x * 256 + threadIdx.x;
    if (e >= N_EDGES) return;
    int d = dst[e];
    int pos = csr_off[d] + atomicAdd(&fill[d], 1);
    csr_eid[pos] = e;
    csr_src[pos] = src[e];
}

// ---------------- fused: logits + online segment softmax + aggregation + head mean ----------------
// one block (4 waves) per destination node; wave h owns head h; lane owns channel
__global__ void __launch_bounds__(256) fused_kernel(const int* __restrict__ csr_off,
                                                    const int* __restrict__ csr_eid,
                                                    const int* __restrict__ csr_src,
                                                    const float* __restrict__ ea,
                                                    const float* __restrict__ xl,
                                                    const float* __restrict__ xr,
                                                    const float* __restrict__ We,
                                                    const float* __restrict__ att,
                                                    const float* __restrict__ bias,
                                                    float* __restrict__ out) {
    int i = blockIdx.x;
    int tid = threadIdx.x;
    int lane = tid & 63;
    int h = tid >> 6;
    int col = tid;                      // h*64 + lane
    int off = csr_off[i];
    int deg = csr_off[i + 1] - off;
    int nc = (deg < MAXD) ? deg : MAXD;

    __shared__ float ea_s[MAXD][D];
    __shared__ int   src_s[MAXD];
    __shared__ int   eid_s[MAXD];
    __shared__ float la_s[D];
    __shared__ float red[H][C];

    for (int j = tid; j < nc; j += 256) {
        eid_s[j] = csr_eid[off + j];
        src_s[j] = csr_src[off + j];
    }
    __syncthreads();
    for (int idx = tid; idx < nc * D; idx += 256) {
        int j = idx >> 4, k = idx & 15;
        ea_s[j][k] = ea[(size_t)eid_s[j] * D + k];
    }
    __syncthreads();
    // self-loop attr = mean of incoming edge_attr
    if (tid < D) {
        float s = 0.f;
        for (int j = 0; j < nc; ++j) s += ea_s[j][tid];
        for (int j = MAXD; j < deg; ++j) s += ea[(size_t)csr_eid[off + j] * D + tid];
        la_s[tid] = s / fmaxf((float)deg, 1.f);
    }
    __syncthreads();

    // per-lane constants: W_e column, att entry, target-row entries
    float we[D];
#pragma unroll
    for (int k = 0; k < D; ++k) we[k] = We[(size_t)k * HC + col];
    float attc = att[col];
    float xr_t = xr[(size_t)i * HC + col];
    float xl_i = xl[(size_t)i * HC + col];

    // self-loop message/logit
    float ee = 0.f;
#pragma unroll
    for (int k = 0; k < D; ++k) ee += la_s[k] * we[k];
    float v = xl_i + xr_t + ee;
    v = (v > 0.f) ? v : NEG_SLOPE * v;
    v *= attc;
#pragma unroll
    for (int o = 32; o > 0; o >>= 1) v += __shfl_xor(v, o, 64);

    float m = v;        // running max (wave-uniform)
    float den = 1.f;    // exp(self - self) = 1
    float acc = xl_i;   // accumulator for this (head, channel)

    for (int j = 0; j < deg; ++j) {
        int s;
        float eav[D];
        if (j < MAXD) {
            s = src_s[j];
#pragma unroll
            for (int k = 0; k < D; ++k) eav[k] = ea_s[j][k];
        } else {
            int e = csr_eid[off + j];
            s = csr_src[off + j];
            for (int k = 0; k < D; ++k) eav[k] = ea[(size_t)e * D + k];
        }
        float xls = xl[(size_t)s * HC + col];     // THE gather (once per edge)
        float u = 0.f;
#pragma unroll
        for (int k = 0; k < D; ++k) u += eav[k] * we[k];
        u += xls + xr_t;
        u = (u > 0.f) ? u : NEG_SLOPE * u;
        u *= attc;
#pragma unroll
        for (int o = 32; o > 0; o >>= 1) u += __shfl_xor(u, o, 64);
        // online softmax update; u is wave-uniform -> no divergence
        if (u > m) {
            float sc = __expf(m - u);
            den = den * sc + 1.f;
            acc = acc * sc + xls;
            m = u;
        } else {
            float w = __expf(u - m);
            den += w;
            acc += w * xls;
        }
    }

    red[h][lane] = acc / den;
    __syncthreads();
    if (tid < C) {
        float o4 = (red[0][tid] + red[1][tid] + red[2][tid] + red[3][tid]) * 0.25f
                   + bias[tid];
        out[(size_t)i * C + tid] = o4;
    }
}

// ---------------- BN statistics (sum, sumsq per channel) ----------------
__global__ void __launch_bounds__(256) bn_stats_kernel(const float* __restrict__ out,
                                                       float* __restrict__ bn) {
    int tid = threadIdx.x;
    int c = tid & 63;
    int r0 = blockIdx.x * 256 + (tid >> 6);
    int rend = (blockIdx.x * 256 + 256 < N_NODES) ? blockIdx.x * 256 + 256 : N_NODES;
    float s = 0.f, s2 = 0.f;
    for (int r = r0; r < rend; r += 4) {
        float v = out[(size_t)r * C + c];
        s += v; s2 += v * v;
    }
    __shared__ float red[256], red2[256];
    red[tid] = s; red2[tid] = s2;
    __syncthreads();
    if (tid < 128) { red[tid] += red[tid + 128]; red2[tid] += red2[tid + 128]; }
    __syncthreads();
    if (tid < 64) {
        atomicAdd(&bn[c], red[tid] + red[tid + 64]);
        atomicAdd(&bn[64 + c], red2[tid] + red2[tid + 64]);
    }
}

// ---------------- BN normalize + residual + ReLU (in place on out) ----------------
__global__ void __launch_bounds__(256) final_kernel(const float* __restrict__ x,
                                                    const float* __restrict__ bn,
                                                    const float* __restrict__ gamma,
                                                    const float* __restrict__ beta,
                                                    float* __restrict__ out) {
    int idx = blockIdx.x * 256 + threadIdx.x;
    if (idx >= N_NODES * C) return;
    int c = idx & 63;
    float mu = bn[c] * (1.f / N_NODES);
    float var = bn[64 + c] * (1.f / N_NODES) - mu * mu;
    float o = out[idx];
    float y = gamma[c] * (o - mu) * rsqrtf(var + BN_EPS) + beta[c] + x[idx];
    out[idx] = fmaxf(y, 0.f);
}

extern "C" void kernel_launch(void* const* d_in, const int* in_sizes, int n_in,
                              void* d_out, int out_size, void* d_ws, size_t ws_size,
                              hipStream_t stream) {
    const float* x     = (const float*)d_in[0];
    const int*   ei    = (const int*)d_in[1];
    const float* ea    = (const float*)d_in[2];
    const float* W_l   = (const float*)d_in[3];
    const float* W_r   = (const float*)d_in[4];
    const float* W_e   = (const float*)d_in[5];
    const float* att   = (const float*)d_in[6];
    const float* bias  = (const float*)d_in[7];
    const float* gamma = (const float*)d_in[8];
    const float* beta  = (const float*)d_in[9];
    float* out = (float*)d_out;

    const int* src = ei;
    const int* dst = ei + N_EDGES;

    char* p = (char*)d_ws;
    float* bn      = (float*)p; p += 512;
    int*   cnt     = (int*)p;   p += (size_t)N_NODES * 4;
    int*   fill    = (int*)p;   p += (size_t)N_NODES * 4;
    int*   csr_off = (int*)p;   p += (size_t)(N_NODES + 4) * 4;
    int*   csr_eid = (int*)p;   p += (size_t)N_EDGES * 4;
    int*   csr_src = (int*)p;   p += (size_t)N_EDGES * 4;
    float* xl      = (float*)p; p += (size_t)N_NODES * HC * 4;
    float* xr      = (float*)p; p += (size_t)N_NODES * HC * 4;

    // zero bn + cnt + fill (contiguous)
    hipMemsetAsync(bn, 0, 512 + 2 * (size_t)N_NODES * 4, stream);

    proj2_kernel<<<N_NODES / 8, 256, 0, stream>>>(x, W_l, W_r, xl, xr);
    cnt_kernel<<<(N_EDGES + 255) / 256, 256, 0, stream>>>(dst, cnt);
    scan_kernel<<<1, 1024, 0, stream>>>(cnt, csr_off);
    csr_fill_kernel<<<(N_EDGES + 255) / 256, 256, 0, stream>>>(src, dst, csr_off, fill,
                                                               csr_eid, csr_src);
    fused_kernel<<<N_NODES, 256, 0, stream>>>(csr_off, csr_eid, csr_src, ea, xl, xr,
                                              W_e, att, bias, out);
    bn_stats_kernel<<<(N_NODES + 255) / 256, 256, 0, stream>>>(out, bn);
    final_kernel<<<(N_NODES * C) / 256, 256, 0, stream>>>(x, bn, gamma, beta, out);
}

// Round 3
// 408.136 us; speedup vs baseline: 3.1229x; 1.5311x over previous
//
#include <hip/hip_runtime.h>
#include <math.h>

#define N_NODES 50000
#define N_EDGES 800000
#define C 64
#define H 4
#define D 16
#define HC 256
#define BN_EPS 1e-5f

// 16-lane (DPP row) rotate-add; after ror8,ror4,ror2,ror1 every lane holds the row sum.
template <int CTRL>
__device__ __forceinline__ float ror_add(float x) {
    int y = __builtin_amdgcn_update_dpp(0, __float_as_int(x), CTRL, 0xF, 0xF, true);
    return x + __int_as_float(y);
}
__device__ __forceinline__ float row_reduce(float u) {
    u = ror_add<0x128>(u);  // ror 8
    u = ror_add<0x124>(u);  // ror 4
    u = ror_add<0x122>(u);  // ror 2
    u = ror_add<0x121>(u);  // ror 1
    return u;
}

// leaky_relu(z, 0.2) == 0.6*z + 0.4*|z|
__device__ __forceinline__ float lrelu(float z) {
    return fmaf(0.4f, fabsf(z), 0.6f * z);
}

// ---------------- fused projection: xl = x@W_l, xr = x@W_r ----------------
__global__ void __launch_bounds__(256) proj2_kernel(const float* __restrict__ x,
                                                    const float* __restrict__ Wl,
                                                    const float* __restrict__ Wr,
                                                    float* __restrict__ xl,
                                                    float* __restrict__ xr) {
    __shared__ float xs[8][C];
    int tid = threadIdx.x;
    int row0 = blockIdx.x * 8;
    for (int i = tid; i < 8 * C; i += 256) {
        int r = i >> 6, k = i & 63;
        xs[r][k] = x[(size_t)(row0 + r) * C + k];
    }
    __syncthreads();
    float al[8] = {0.f}, ar[8] = {0.f};
    for (int k = 0; k < C; ++k) {
        float wl = Wl[(size_t)k * HC + tid];
        float wr = Wr[(size_t)k * HC + tid];
#pragma unroll
        for (int r = 0; r < 8; ++r) { al[r] += xs[r][k] * wl; ar[r] += xs[r][k] * wr; }
    }
#pragma unroll
    for (int r = 0; r < 8; ++r) {
        xl[(size_t)(row0 + r) * HC + tid] = al[r];
        xr[(size_t)(row0 + r) * HC + tid] = ar[r];
    }
}

// ---------------- per-dst edge counts ----------------
__global__ void __launch_bounds__(256) cnt_kernel(const int* __restrict__ dst,
                                                  int* __restrict__ cnt) {
    int e = blockIdx.x * 256 + threadIdx.x;
    if (e < N_EDGES) atomicAdd(&cnt[dst[e]], 1);
}

// ---------------- exclusive prefix sum over cnt -> csr_off ----------------
__global__ void scan_kernel(const int* __restrict__ cnt, int* __restrict__ off) {
    __shared__ int wsum[16];
    __shared__ int carry_s;
    int tid = threadIdx.x;
    int lane = tid & 63;
    int w = tid >> 6;
    if (tid == 0) { carry_s = 0; off[0] = 0; }
    __syncthreads();
    for (int base = 0; base < N_NODES; base += 1024) {
        int i = base + tid;
        int v = (i < N_NODES) ? cnt[i] : 0;
        int xv = v;
        for (int o = 1; o < 64; o <<= 1) {
            int t = __shfl_up(xv, o, 64);
            if (lane >= o) xv += t;
        }
        if (lane == 63) wsum[w] = xv;
        __syncthreads();
        if (w == 0 && lane < 16) {
            int y = wsum[lane];
            for (int o = 1; o < 16; o <<= 1) {
                int t = __shfl_up(y, o, 64);
                if (lane >= o) y += t;
            }
            wsum[lane] = y;
        }
        __syncthreads();
        int prefix = carry_s + ((w > 0) ? wsum[w - 1] : 0);
        if (i < N_NODES) off[i + 1] = prefix + xv;
        __syncthreads();
        if (tid == 1023) carry_s = prefix + xv;
        __syncthreads();
    }
}

// ---------------- CSR fill: (edge id, src id) packed per slot ----------------
__global__ void __launch_bounds__(256) csr_fill_kernel(const int* __restrict__ src,
                                                       const int* __restrict__ dst,
                                                       const int* __restrict__ csr_off,
                                                       int* __restrict__ fill,
                                                       int2* __restrict__ csr_es) {
    int e = blockIdx.x * 256 + threadIdx.x;
    if (e >= N_EDGES) return;
    int d = dst[e];
    int pos = csr_off[d] + atomicAdd(&fill[d], 1);
    csr_es[pos] = make_int2(e, src[e]);
}

// ---------------- fused GATv2: one wave per node, zero LDS ----------------
// lane l: head h = l>>4, channels (l&15)*4 .. +3 of head h.
__global__ void __launch_bounds__(256) fused_kernel(const int* __restrict__ csr_off,
                                                    const int2* __restrict__ csr_es,
                                                    const float* __restrict__ ea,
                                                    const float* __restrict__ xl,
                                                    const float* __restrict__ xr,
                                                    const float* __restrict__ We,
                                                    const float* __restrict__ att,
                                                    const float* __restrict__ bias,
                                                    float* __restrict__ out) {
    int gtid = blockIdx.x * blockDim.x + threadIdx.x;
    int gw = gtid >> 6;
    int nw = (gridDim.x * blockDim.x) >> 6;
    int lane = threadIdx.x & 63;
    int c0 = lane & 15;
    int colbase = (lane >> 4) * C + c0 * 4;

    // per-lane weight columns: We[k][colbase + 0..3], k = 0..15  (64 VGPRs)
    float w0[D], w1[D], w2[D], w3[D];
#pragma unroll
    for (int k = 0; k < D; ++k) {
        float4 w = *(const float4*)(We + (size_t)k * HC + colbase);
        w0[k] = w.x; w1[k] = w.y; w2[k] = w.z; w3[k] = w.w;
    }
    float4 av = *(const float4*)(att + colbase);
    float4 bv = *(const float4*)(bias + c0 * 4);

    for (int i = gw; i < N_NODES; i += nw) {
        int off = csr_off[i];
        int deg = csr_off[i + 1] - off;
        float4 xrt = *(const float4*)(xr + (size_t)i * HC + colbase);
        float4 xli = *(const float4*)(xl + (size_t)i * HC + colbase);

        float m = -1e30f, den = 0.f;
        float a0 = 0.f, a1 = 0.f, a2 = 0.f, a3 = 0.f;      // weighted aggregation
        float s0 = 0.f, s1 = 0.f, s2 = 0.f, s3 = 0.f;      // sum of per-edge ee (self loop)

        int2 esn = (deg > 0) ? csr_es[off] : make_int2(0, 0);
        for (int j = 0; j < deg; ++j) {
            int2 es = esn;
            if (j + 1 < deg) esn = csr_es[off + j + 1];
            int e    = __builtin_amdgcn_readfirstlane(es.x);
            int sidx = __builtin_amdgcn_readfirstlane(es.y);

            const float* er = ea + (size_t)e * D;
            float eav[D];
#pragma unroll
            for (int q = 0; q < 4; ++q) *(float4*)(eav + 4 * q) = ((const float4*)er)[q];
            float4 xs = *(const float4*)(xl + (size_t)sidx * HC + colbase);

            float e0 = 0.f, e1 = 0.f, e2 = 0.f, e3 = 0.f;
#pragma unroll
            for (int k = 0; k < D; ++k) {
                e0 = fmaf(eav[k], w0[k], e0);
                e1 = fmaf(eav[k], w1[k], e1);
                e2 = fmaf(eav[k], w2[k], e2);
                e3 = fmaf(eav[k], w3[k], e3);
            }
            s0 += e0; s1 += e1; s2 += e2; s3 += e3;

            float z0 = e0 + xs.x + xrt.x;
            float z1 = e1 + xs.y + xrt.y;
            float z2 = e2 + xs.z + xrt.z;
            float z3 = e3 + xs.w + xrt.w;
            float u = lrelu(z0) * av.x;
            u = fmaf(lrelu(z1), av.y, u);
            u = fmaf(lrelu(z2), av.z, u);
            u = fmaf(lrelu(z3), av.w, u);
            u = row_reduce(u);                 // logit for this (edge, head), all lanes

            float mn = fmaxf(m, u);
            float so = __expf(m - mn);
            float wt = __expf(u - mn);
            den = fmaf(den, so, wt);
            a0 = fmaf(a0, so, wt * xs.x);
            a1 = fmaf(a1, so, wt * xs.y);
            a2 = fmaf(a2, so, wt * xs.z);
            a3 = fmaf(a3, so, wt * xs.w);
            m = mn;
        }

        // ---- self loop: loop_attr = mean(ea) -> ee_self = mean(ee_j) by linearity ----
        float dninv = 1.f / fmaxf((float)deg, 1.f);
        {
            float z0 = s0 * dninv + xli.x + xrt.x;
            float z1 = s1 * dninv + xli.y + xrt.y;
            float z2 = s2 * dninv + xli.z + xrt.z;
            float z3 = s3 * dninv + xli.w + xrt.w;
            float u = lrelu(z0) * av.x;
            u = fmaf(lrelu(z1), av.y, u);
            u = fmaf(lrelu(z2), av.z, u);
            u = fmaf(lrelu(z3), av.w, u);
            u = row_reduce(u);
            float mn = fmaxf(m, u);
            float so = __expf(m - mn);
            float wt = __expf(u - mn);
            den = fmaf(den, so, wt);
            a0 = fmaf(a0, so, wt * xli.x);
            a1 = fmaf(a1, so, wt * xli.y);
            a2 = fmaf(a2, so, wt * xli.z);
            a3 = fmaf(a3, so, wt * xli.w);
        }

        // ---- normalize, head mean, bias, store ----
        float inv = 1.f / den;
        float r0 = a0 * inv, r1 = a1 * inv, r2 = a2 * inv, r3 = a3 * inv;
        r0 += __shfl_xor(r0, 16); r0 += __shfl_xor(r0, 32);
        r1 += __shfl_xor(r1, 16); r1 += __shfl_xor(r1, 32);
        r2 += __shfl_xor(r2, 16); r2 += __shfl_xor(r2, 32);
        r3 += __shfl_xor(r3, 16); r3 += __shfl_xor(r3, 32);
        if (lane < 16) {
            float4 o;
            o.x = fmaf(r0, 0.25f, bv.x);
            o.y = fmaf(r1, 0.25f, bv.y);
            o.z = fmaf(r2, 0.25f, bv.z);
            o.w = fmaf(r3, 0.25f, bv.w);
            *(float4*)(out + (size_t)i * C + c0 * 4) = o;
        }
    }
}

// ---------------- BN statistics (sum, sumsq per channel) ----------------
__global__ void __launch_bounds__(256) bn_stats_kernel(const float* __restrict__ out,
                                                       float* __restrict__ bn) {
    int tid = threadIdx.x;
    int c = tid & 63;
    int r0 = blockIdx.x * 256 + (tid >> 6);
    int rend = (blockIdx.x * 256 + 256 < N_NODES) ? blockIdx.x * 256 + 256 : N_NODES;
    float s = 0.f, s2 = 0.f;
    for (int r = r0; r < rend; r += 4) {
        float v = out[(size_t)r * C + c];
        s += v; s2 += v * v;
    }
    __shared__ float red[256], red2[256];
    red[tid] = s; red2[tid] = s2;
    __syncthreads();
    if (tid < 128) { red[tid] += red[tid + 128]; red2[tid] += red2[tid + 128]; }
    __syncthreads();
    if (tid < 64) {
        atomicAdd(&bn[c], red[tid] + red[tid + 64]);
        atomicAdd(&bn[64 + c], red2[tid] + red2[tid + 64]);
    }
}

// ---------------- BN normalize + residual + ReLU (in place on out) ----------------
__global__ void __launch_bounds__(256) final_kernel(const float* __restrict__ x,
                                                    const float* __restrict__ bn,
                                                    const float* __restrict__ gamma,
                                                    const float* __restrict__ beta,
                                                    float* __restrict__ out) {
    int idx = blockIdx.x * 256 + threadIdx.x;
    if (idx >= N_NODES * C) return;
    int c = idx & 63;
    float mu = bn[c] * (1.f / N_NODES);
    float var = bn[64 + c] * (1.f / N_NODES) - mu * mu;
    float o = out[idx];
    float y = gamma[c] * (o - mu) * rsqrtf(var + BN_EPS) + beta[c] + x[idx];
    out[idx] = fmaxf(y, 0.f);
}

extern "C" void kernel_launch(void* const* d_in, const int* in_sizes, int n_in,
                              void* d_out, int out_size, void* d_ws, size_t ws_size,
                              hipStream_t stream) {
    const float* x     = (const float*)d_in[0];
    const int*   ei    = (const int*)d_in[1];
    const float* ea    = (const float*)d_in[2];
    const float* W_l   = (const float*)d_in[3];
    const float* W_r   = (const float*)d_in[4];
    const float* W_e   = (const float*)d_in[5];
    const float* att   = (const float*)d_in[6];
    const float* bias  = (const float*)d_in[7];
    const float* gamma = (const float*)d_in[8];
    const float* beta  = (const float*)d_in[9];
    float* out = (float*)d_out;

    const int* src = ei;
    const int* dst = ei + N_EDGES;

    char* p = (char*)d_ws;
    float* bn      = (float*)p; p += 512;
    int*   cnt     = (int*)p;   p += (size_t)N_NODES * 4;
    int*   fill    = (int*)p;   p += (size_t)N_NODES * 4;
    int*   csr_off = (int*)p;   p += (size_t)(N_NODES + 4) * 4;
    int2*  csr_es  = (int2*)p;  p += (size_t)N_EDGES * 8;
    float* xl      = (float*)p; p += (size_t)N_NODES * HC * 4;
    float* xr      = (float*)p; p += (size_t)N_NODES * HC * 4;

    // zero bn + cnt + fill (contiguous)
    hipMemsetAsync(bn, 0, 512 + 2 * (size_t)N_NODES * 4, stream);

    proj2_kernel<<<N_NODES / 8, 256, 0, stream>>>(x, W_l, W_r, xl, xr);
    cnt_kernel<<<(N_EDGES + 255) / 256, 256, 0, stream>>>(dst, cnt);
    scan_kernel<<<1, 1024, 0, stream>>>(cnt, csr_off);
    csr_fill_kernel<<<(N_EDGES + 255) / 256, 256, 0, stream>>>(src, dst, csr_off, fill,
                                                               csr_es);
    fused_kernel<<<2048, 256, 0, stream>>>(csr_off, csr_es, ea, xl, xr, W_e, att, bias,
                                           out);
    bn_stats_kernel<<<(N_NODES + 255) / 256, 256, 0, stream>>>(out, bn);
    final_kernel<<<(N_NODES * C) / 256, 256, 0, stream>>>(x, bn, gamma, beta, out);
}